// Round 7
// baseline (298.304 us; speedup 1.0000x reference)
//
#include <hip/hip_runtime.h>

#define N 20000
#define E 200000
#define IN 128
#define OUT 128
#define NB 8
#define SI 16
#define SO 16
#define R 230
#define T 365

// Scratch in module .bss (zero-initialized at load). d_ws untouched;
// kernel_launch does plain kernel launches only (graph-capture safe).
// Counter invariant: node_kernel's tail re-zeroes all counters + g_done for
// the NEXT launch; the first launch rides .bss zero-init.
__device__ float  g_W_t[(size_t)R * NB * SO * SI]; // W transposed: [r][b][ol][i]
__device__ ushort g_msg[(size_t)E * OUT];          // messages (bf16), dst-sorted
__device__ int    g_cnt_d[N];
__device__ int    g_off_d[N];
__device__ int    g_cur_d[N];
__device__ int    g_cnt_r[R * 16];                 // line-padded
__device__ int    g_cur_r[R * 16];
__device__ int    g_pos[E];                        // e -> dst-sorted position
__device__ int    g_eid_r[E];                      // edge ids sorted by relation
__device__ int    g_total_d;
__device__ int    g_total_r;
__device__ unsigned g_done;

__device__ __forceinline__ ushort f2bf(float f) {  // RNE float->bf16
    unsigned u = __float_as_uint(f);
    return (ushort)((u + 0x7fffu + ((u >> 16) & 1u)) >> 16);
}
__device__ __forceinline__ float bf2f(ushort v) {
    return __uint_as_float((unsigned)v << 16);
}
__device__ __forceinline__ float bflo(unsigned m) {       // low ushort (feature 2q)
    return __uint_as_float(m << 16);
}
__device__ __forceinline__ float bfhi(unsigned m) {       // high ushort (feature 2q+1)
    return __uint_as_float(m & 0xffff0000u);
}

// Histograms + W transpose; LAST block (atomic done-counter) additionally
// runs the wave-aggregated bump allocation — fuses the former alloc_kernel
// launch. No co-residency assumption: blocks retire normally.
__global__ __launch_bounds__(256) void build_kernel(
        const float* __restrict__ weight,
        const int* __restrict__ edge_dst,
        const int* __restrict__ edge_type) {
    __shared__ int lh[R];
    __shared__ int s_last;
    const int tid  = threadIdx.x;
    const int gtid = blockIdx.x * 256 + tid;
    const int GSZ  = gridDim.x * 256;

    // W transpose into [r][b][ol][i]
    for (int t = gtid; t < R * NB * SI * SO; t += GSZ) {
        int r  = t >> 11;
        int b  = (t >> 8) & 7;
        int ol = (t >> 4) & 15;
        int i  = t & 15;
        g_W_t[t] = weight[(long)r * 2048 + b * 256 + i * 16 + ol];
    }
    for (int j = tid; j < R; j += 256) lh[j] = 0;
    __syncthreads();
    for (int e = gtid; e < E; e += GSZ) {
        atomicAdd(&g_cnt_d[edge_dst[e]], 1);
        atomicAdd(&lh[edge_type[e]], 1);
    }
    __syncthreads();
    for (int j = tid; j < R; j += 256)
        if (lh[j]) atomicAdd(&g_cnt_r[j * 16], lh[j]);

    // ---- completion detection: last block does the allocation ----
    __syncthreads();
    if (tid == 0) {
        __threadfence();
        unsigned d = atomicAdd(&g_done, 1u);
        s_last = (d == (unsigned)(gridDim.x - 1)) ? 1 : 0;
    }
    __syncthreads();
    if (!s_last) return;
    __threadfence();                                  // acquire side

    const int lane = tid & 63;
    for (int idx = tid; idx < 20032; idx += 256) {    // wave-aligned chunks
        int c = (idx < N) ? __hip_atomic_load(&g_cnt_d[idx], __ATOMIC_RELAXED,
                                              __HIP_MEMORY_SCOPE_AGENT) : 0;
        int x = c;
        for (int d = 1; d < 64; d <<= 1) {
            int y = __shfl_up(x, d);
            if (lane >= d) x += y;
        }
        int bse = 0;
        if (lane == 63) bse = atomicAdd(&g_total_d, x);
        bse = __shfl(bse, 63);
        if (idx < N) {
            int off = bse + x - c;
            g_off_d[idx] = off;
            g_cur_d[idx] = off;
        }
    }
    {
        int j = tid;                                   // 256 covers R=230
        int c = (j < R) ? __hip_atomic_load(&g_cnt_r[j * 16], __ATOMIC_RELAXED,
                                            __HIP_MEMORY_SCOPE_AGENT) : 0;
        int x = c;
        for (int d = 1; d < 64; d <<= 1) {
            int y = __shfl_up(x, d);
            if (lane >= d) x += y;
        }
        int bse = 0;
        if (lane == 63) bse = atomicAdd(&g_total_r, x);
        bse = __shfl(bse, 63);
        if (j < R) g_cur_r[j * 16] = bse + x - c;
    }
}

__global__ void scatter_kernel(const int* __restrict__ edge_dst,
                               const int* __restrict__ edge_type) {
    int e = blockIdx.x * blockDim.x + threadIdx.x;
    if (e < E) {
        g_pos[e] = atomicAdd(&g_cur_d[edge_dst[e]], 1);
        int pr = atomicAdd(&g_cur_r[edge_type[e] * 16], 1);
        g_eid_r[pr] = e;
    }
}

// Block-pipelined message kernel, 32-edge tiles (verified round 6).
__global__ __launch_bounds__(256) void msg_kernel(
        const float* __restrict__ h,
        const float* __restrict__ edge_norm,
        const int* __restrict__ edge_src,
        const int* __restrict__ edge_type) {
    __shared__ __attribute__((aligned(16))) float hsm[32 * 132];
    __shared__ int   ssrc[32], stype[32], spos[32];
    __shared__ float snorm[32];

    const int tid = threadIdx.x;
    const int lo  = blockIdx.x * 32;

    if (tid < 32) {
        int e = g_eid_r[lo + tid];
        ssrc[tid]  = edge_src[e];
        stype[tid] = edge_type[e];
        snorm[tid] = edge_norm[e];
        spos[tid]  = g_pos[e];
    }
    __syncthreads();

    {   // gather 32 h-rows: 8 threads/row, 4 float4 each
        const int row = tid >> 3;
        const int c0  = (tid & 7) * 4;
        const float* hp = h + (long)ssrc[row] * IN;
        float* dst = &hsm[row * 132];
#pragma unroll
        for (int j = 0; j < 4; ++j) {
            float4 v = *reinterpret_cast<const float4*>(hp + c0 + 32 * j);
            *reinterpret_cast<float4*>(dst + c0 + 32 * j) = v;
        }
    }
    __syncthreads();

    const int slot = tid >> 7;           // 0,1
    const int o    = tid & 127;
    const int b    = o >> 4;
    const int ol   = o & 15;

#define MSG_BODY(K, W0, W1, W2, W3)                                          \
    {                                                                        \
        const float* hrow = &hsm[(K) * 132 + b * 16];                        \
        float4 h0 = *reinterpret_cast<const float4*>(hrow);                  \
        float4 h1 = *reinterpret_cast<const float4*>(hrow + 4);              \
        float4 h2 = *reinterpret_cast<const float4*>(hrow + 8);              \
        float4 h3 = *reinterpret_cast<const float4*>(hrow + 12);             \
        float m0 = 0.f, m1 = 0.f;                                            \
        m0 = fmaf(h0.x, W0.x, m0); m0 = fmaf(h0.y, W0.y, m0);                \
        m0 = fmaf(h0.z, W0.z, m0); m0 = fmaf(h0.w, W0.w, m0);                \
        m1 = fmaf(h1.x, W1.x, m1); m1 = fmaf(h1.y, W1.y, m1);                \
        m1 = fmaf(h1.z, W1.z, m1); m1 = fmaf(h1.w, W1.w, m1);                \
        m0 = fmaf(h2.x, W2.x, m0); m0 = fmaf(h2.y, W2.y, m0);                \
        m0 = fmaf(h2.z, W2.z, m0); m0 = fmaf(h2.w, W2.w, m0);                \
        m1 = fmaf(h3.x, W3.x, m1); m1 = fmaf(h3.y, W3.y, m1);                \
        m1 = fmaf(h3.z, W3.z, m1); m1 = fmaf(h3.w, W3.w, m1);                \
        __builtin_nontemporal_store(f2bf(snorm[K] * (m0 + m1)),              \
                                    &g_msg[(long)spos[K] * OUT + o]);        \
    }

    if (stype[0] == stype[31]) {
        const float4* wp = reinterpret_cast<const float4*>(
            g_W_t + (long)stype[0] * 2048 + b * 256 + ol * 16);
        float4 w0 = wp[0], w1 = wp[1], w2 = wp[2], w3 = wp[3];
#pragma unroll 4
        for (int k = slot; k < 32; k += 2)
            MSG_BODY(k, w0, w1, w2, w3)
    } else {
        int rcur = -1;
        float4 w0, w1, w2, w3;
        for (int k = slot; k < 32; k += 2) {
            int r = stype[k];
            if (r != rcur) {
                const float4* wp = reinterpret_cast<const float4*>(
                    g_W_t + (long)r * 2048 + b * 256 + ol * 16);
                w0 = wp[0]; w1 = wp[1]; w2 = wp[2]; w3 = wp[3];
                rcur = r;
            }
            MSG_BODY(k, w0, w1, w2, w3)
        }
    }
#undef MSG_BODY
}

// Latency-rebuilt node kernel: 16 nodes/block, 256 threads = 4 waves x
// (64 feature-pairs). Each wave owns 4 independent nodes. No LDS, no
// barriers (except tail), no bank conflicts. msg read as uint bf16-pairs
// (4B/lane coalesced); h via wave-broadcast float4; loop_weight / bias /
// time_embed / out all float2 (512B per wave-instr).
__global__ __launch_bounds__(256) void node_kernel(
        const float* __restrict__ h,
        const float* __restrict__ node_norm,
        const float* __restrict__ h_bias,
        const float* __restrict__ loop_weight,
        const float* __restrict__ time_embed,
        const int* __restrict__ time_idx,
        float* __restrict__ out) {
    const int t    = threadIdx.x;
    const int q    = t & 63;             // feature pair: features 2q, 2q+1
    const int grp  = t >> 6;             // 0..3
    const int base = blockIdx.x * 16 + grp * 4;

    const unsigned* msg32 = reinterpret_cast<const unsigned*>(g_msg);

    // ---- segment sums (msg rows contiguous per node) ----
    float accL[4], accH[4];
#pragma unroll
    for (int nl = 0; nl < 4; ++nl) {
        const int n  = base + nl;
        const int st = g_off_d[n];
        const int cn = g_cnt_d[n];
        const unsigned* mp = msg32 + (size_t)st * 64 + q;
        float aL0 = 0.f, aL1 = 0.f, aH0 = 0.f, aH1 = 0.f;
        int k = 0;
        for (; k + 3 < cn; k += 4) {
            unsigned m0 = __builtin_nontemporal_load(mp + (size_t)(k + 0) * 64);
            unsigned m1 = __builtin_nontemporal_load(mp + (size_t)(k + 1) * 64);
            unsigned m2 = __builtin_nontemporal_load(mp + (size_t)(k + 2) * 64);
            unsigned m3 = __builtin_nontemporal_load(mp + (size_t)(k + 3) * 64);
            aL0 += bflo(m0); aH0 += bfhi(m0);
            aL1 += bflo(m1); aH1 += bfhi(m1);
            aL0 += bflo(m2); aH0 += bfhi(m2);
            aL1 += bflo(m3); aH1 += bfhi(m3);
        }
        for (; k < cn; ++k) {
            unsigned m = __builtin_nontemporal_load(mp + (size_t)k * 64);
            aL0 += bflo(m); aH0 += bfhi(m);
        }
        float nn = node_norm[n];
        accL[nl] = (aL0 + aL1) * nn;
        accH[nl] = (aH0 + aH1) * nn;
    }

    // ---- self-loop GEMM: h broadcast float4, loop_weight float2 ----
    float slL0 = 0.f, slL1 = 0.f, slL2 = 0.f, slL3 = 0.f;
    float slH0 = 0.f, slH1 = 0.f, slH2 = 0.f, slH3 = 0.f;
    const float2* lw2 = reinterpret_cast<const float2*>(loop_weight);
    const float* hp0 = h + (size_t)(base + 0) * IN;
    const float* hp1 = h + (size_t)(base + 1) * IN;
    const float* hp2 = h + (size_t)(base + 2) * IN;
    const float* hp3 = h + (size_t)(base + 3) * IN;
#pragma unroll 4
    for (int i0 = 0; i0 < IN; i0 += 4) {
        float2 w0 = lw2[(size_t)(i0 + 0) * 64 + q];
        float2 w1 = lw2[(size_t)(i0 + 1) * 64 + q];
        float2 w2 = lw2[(size_t)(i0 + 2) * 64 + q];
        float2 w3 = lw2[(size_t)(i0 + 3) * 64 + q];
        float4 v0 = *reinterpret_cast<const float4*>(hp0 + i0);
        float4 v1 = *reinterpret_cast<const float4*>(hp1 + i0);
        float4 v2 = *reinterpret_cast<const float4*>(hp2 + i0);
        float4 v3 = *reinterpret_cast<const float4*>(hp3 + i0);
        slL0 = fmaf(v0.x, w0.x, slL0); slL0 = fmaf(v0.y, w1.x, slL0);
        slL0 = fmaf(v0.z, w2.x, slL0); slL0 = fmaf(v0.w, w3.x, slL0);
        slH0 = fmaf(v0.x, w0.y, slH0); slH0 = fmaf(v0.y, w1.y, slH0);
        slH0 = fmaf(v0.z, w2.y, slH0); slH0 = fmaf(v0.w, w3.y, slH0);
        slL1 = fmaf(v1.x, w0.x, slL1); slL1 = fmaf(v1.y, w1.x, slL1);
        slL1 = fmaf(v1.z, w2.x, slL1); slL1 = fmaf(v1.w, w3.x, slL1);
        slH1 = fmaf(v1.x, w0.y, slH1); slH1 = fmaf(v1.y, w1.y, slH1);
        slH1 = fmaf(v1.z, w2.y, slH1); slH1 = fmaf(v1.w, w3.y, slH1);
        slL2 = fmaf(v2.x, w0.x, slL2); slL2 = fmaf(v2.y, w1.x, slL2);
        slL2 = fmaf(v2.z, w2.x, slL2); slL2 = fmaf(v2.w, w3.x, slL2);
        slH2 = fmaf(v2.x, w0.y, slH2); slH2 = fmaf(v2.y, w1.y, slH2);
        slH2 = fmaf(v2.z, w2.y, slH2); slH2 = fmaf(v2.w, w3.y, slH2);
        slL3 = fmaf(v3.x, w0.x, slL3); slL3 = fmaf(v3.y, w1.x, slL3);
        slL3 = fmaf(v3.z, w2.x, slL3); slL3 = fmaf(v3.w, w3.x, slL3);
        slH3 = fmaf(v3.x, w0.y, slH3); slH3 = fmaf(v3.y, w1.y, slH3);
        slH3 = fmaf(v3.z, w2.y, slH3); slH3 = fmaf(v3.w, w3.y, slH3);
    }
    float slL[4] = {slL0, slL1, slL2, slL3};
    float slH[4] = {slH0, slH1, slH2, slH3};

    // ---- epilogue + time-embedding gather, float2 stores ----
    const float2 bias = reinterpret_cast<const float2*>(h_bias)[q];
    float2* o2  = reinterpret_cast<float2*>(out);
    float2* o2b = reinterpret_cast<float2*>(out + (size_t)N * OUT);
    const float2* te2 = reinterpret_cast<const float2*>(time_embed);
#pragma unroll
    for (int nl = 0; nl < 4; ++nl) {
        const int n = base + nl;
        float2 v;
        v.x = fmaxf(accL[nl] + bias.x + slL[nl], 0.f);
        v.y = fmaxf(accH[nl] + bias.y + slH[nl], 0.f);
        o2[(size_t)n * 64 + q] = v;
        o2b[(size_t)n * 64 + q] = te2[(size_t)time_idx[n] * 64 + q];
    }

    // ---- next-launch counter zeroing (after all g_cnt_d reads) ----
    __syncthreads();
    if (t < 16) g_cnt_d[blockIdx.x * 16 + t] = 0;
    {
        int j = blockIdx.x * 256 + t;           // blocks 0..14 cover R*16
        if (j < R * 16) g_cnt_r[j] = 0;
    }
    if (blockIdx.x == 0 && t == 0) {
        g_total_d = 0; g_total_r = 0; g_done = 0u;
    }
}

extern "C" void kernel_launch(void* const* d_in, const int* in_sizes, int n_in,
                              void* d_out, int out_size, void* d_ws, size_t ws_size,
                              hipStream_t stream) {
    const float* h           = (const float*)d_in[0];
    const float* edge_norm   = (const float*)d_in[1];
    const float* node_norm   = (const float*)d_in[2];
    const float* weight      = (const float*)d_in[3];
    const float* h_bias      = (const float*)d_in[4];
    const float* loop_weight = (const float*)d_in[5];
    const float* time_embed  = (const float*)d_in[6];
    const int*   edge_src    = (const int*)d_in[7];
    const int*   edge_dst    = (const int*)d_in[8];
    const int*   edge_type   = (const int*)d_in[9];
    const int*   time_idx    = (const int*)d_in[10];
    float* out = (float*)d_out;

    build_kernel<<<400, 256, 0, stream>>>(weight, edge_dst, edge_type);
    scatter_kernel<<<(E + 255) / 256, 256, 0, stream>>>(edge_dst, edge_type);
    msg_kernel<<<E / 32, 256, 0, stream>>>(h, edge_norm, edge_src, edge_type);
    node_kernel<<<N / 16, 256, 0, stream>>>(h, node_norm, h_bias, loop_weight,
                                            time_embed, time_idx, out);
}

// Round 8
// 284.938 us; speedup vs baseline: 1.0469x; 1.0469x over previous
//
#include <hip/hip_runtime.h>

#define N 20000
#define E 200000
#define IN 128
#define OUT 128
#define NB 8
#define SI 16
#define SO 16
#define R 230
#define T 365

#define NSH 8                 // relation cursor shards (contention /8)
#define NSEG (R * NSH)        // 1840 (r,shard) segments

// Scratch in module .bss (zero-initialized at load). d_ws untouched;
// kernel_launch does plain kernel launches only (graph-capture safe).
// Counter invariant: node_kernel's tail re-zeroes all counters + g_done for
// the NEXT launch; the first launch rides .bss zero-init.
__device__ float  g_W_t[(size_t)R * NB * SO * SI]; // W transposed: [r][b][ol][i]
__device__ ushort g_msg[(size_t)E * OUT];          // messages (bf16), dst-sorted
__device__ int    g_cnt_d[N];
__device__ int    g_off_d[N];
__device__ int    g_cur_d[N];
__device__ int    g_cnt_r[NSEG * 16];              // line-padded (r,shard) counts
__device__ int    g_cur_r[NSEG * 16];
__device__ int    g_pos[E];                        // e -> dst-sorted position
__device__ int    g_eid_r[E];                      // edge ids, (r,shard)-sorted
__device__ unsigned g_done;

__device__ __forceinline__ ushort f2bf(float f) {  // RNE float->bf16
    unsigned u = __float_as_uint(f);
    return (ushort)((u + 0x7fffu + ((u >> 16) & 1u)) >> 16);
}
__device__ __forceinline__ float bflo(unsigned m) { return __uint_as_float(m << 16); }
__device__ __forceinline__ float bfhi(unsigned m) { return __uint_as_float(m & 0xffff0000u); }
__device__ __forceinline__ int ld_agent(const int* p) {
    return __hip_atomic_load(p, __ATOMIC_RELAXED, __HIP_MEMORY_SCOPE_AGENT);
}

// Histograms + W transpose; LAST finishing block (atomic done-counter) runs
// the offset allocation as a PARALLEL 256-thread two-level scan (round 7's
// serial per-wave-atomic tail was the 95 us bug). No co-residency assumption.
__global__ __launch_bounds__(256) void build_kernel(
        const float* __restrict__ weight,
        const int* __restrict__ edge_dst,
        const int* __restrict__ edge_type) {
    __shared__ int lh[NSEG];          // 7.36 KB per-block rel histogram
    __shared__ int sscan[256];
    __shared__ int s_last;
    const int tid  = threadIdx.x;
    const int gtid = blockIdx.x * 256 + tid;
    const int GSZ  = gridDim.x * 256;

    // W transpose into [r][b][ol][i]
    for (int t = gtid; t < R * NB * SI * SO; t += GSZ) {
        int r  = t >> 11;
        int b  = (t >> 8) & 7;
        int ol = (t >> 4) & 15;
        int i  = t & 15;
        g_W_t[t] = weight[(long)r * 2048 + b * 256 + i * 16 + ol];
    }
    for (int j = tid; j < NSEG; j += 256) lh[j] = 0;
    __syncthreads();
    for (int e = gtid; e < E; e += GSZ) {
        atomicAdd(&g_cnt_d[edge_dst[e]], 1);
        atomicAdd(&lh[edge_type[e] * NSH + (e & (NSH - 1))], 1);
    }
    __syncthreads();
    for (int j = tid; j < NSEG; j += 256)
        if (lh[j]) atomicAdd(&g_cnt_r[j * 16], lh[j]);

    // ---- completion detection: last block allocates ----
    __syncthreads();
    if (tid == 0) {
        __threadfence();
        unsigned d = atomicAdd(&g_done, 1u);
        s_last = (d == (unsigned)(gridDim.x - 1)) ? 1 : 0;
    }
    __syncthreads();
    if (!s_last) return;
    __threadfence();

    // ---- dst offsets: chunk-sum -> LDS scan -> chunk walk ----
    {
        const int CH = 79;                         // 256*79 = 20224 >= N
        const int lo = tid * CH;
        const int hi = (lo + CH < N) ? lo + CH : N;
        int sum = 0;
        for (int i = lo; i < hi; ++i) sum += ld_agent(&g_cnt_d[i]);
        sscan[tid] = sum;
        __syncthreads();
        for (int d = 1; d < 256; d <<= 1) {
            int v = (tid >= d) ? sscan[tid - d] : 0;
            __syncthreads();
            sscan[tid] += v;
            __syncthreads();
        }
        int run = (tid > 0) ? sscan[tid - 1] : 0;
        for (int i = lo; i < hi; ++i) {
            int c = ld_agent(&g_cnt_d[i]);
            g_off_d[i] = run;
            g_cur_d[i] = run;
            run += c;
        }
    }
    __syncthreads();
    // ---- (r,shard) offsets: same pattern over 1840 counters ----
    {
        const int CH = 8;                          // 256*8 = 2048 >= NSEG
        const int lo = tid * CH;
        const int hi = (lo + CH < NSEG) ? lo + CH : NSEG;
        int sum = 0;
        for (int j = lo; j < hi; ++j) sum += ld_agent(&g_cnt_r[j * 16]);
        sscan[tid] = sum;
        __syncthreads();
        for (int d = 1; d < 256; d <<= 1) {
            int v = (tid >= d) ? sscan[tid - d] : 0;
            __syncthreads();
            sscan[tid] += v;
            __syncthreads();
        }
        int run = (tid > 0) ? sscan[tid - 1] : 0;
        for (int j = lo; j < hi; ++j) {
            int c = ld_agent(&g_cnt_r[j * 16]);
            g_cur_r[j * 16] = run;
            run += c;
        }
    }
}

__global__ void scatter_kernel(const int* __restrict__ edge_dst,
                               const int* __restrict__ edge_type) {
    int e = blockIdx.x * blockDim.x + threadIdx.x;
    if (e < E) {
        g_pos[e] = atomicAdd(&g_cur_d[edge_dst[e]], 1);
        int seg = edge_type[e] * NSH + (e & (NSH - 1));
        int pr = atomicAdd(&g_cur_r[seg * 16], 1);
        g_eid_r[pr] = e;
    }
}

// Block-pipelined message kernel, 32-edge tiles (verified rounds 6-7).
__global__ __launch_bounds__(256) void msg_kernel(
        const float* __restrict__ h,
        const float* __restrict__ edge_norm,
        const int* __restrict__ edge_src,
        const int* __restrict__ edge_type) {
    __shared__ __attribute__((aligned(16))) float hsm[32 * 132];
    __shared__ int   ssrc[32], stype[32], spos[32];
    __shared__ float snorm[32];

    const int tid = threadIdx.x;
    const int lo  = blockIdx.x * 32;

    if (tid < 32) {
        int e = g_eid_r[lo + tid];
        ssrc[tid]  = edge_src[e];
        stype[tid] = edge_type[e];
        snorm[tid] = edge_norm[e];
        spos[tid]  = g_pos[e];
    }
    __syncthreads();

    {   // gather 32 h-rows: 8 threads/row, 4 float4 each
        const int row = tid >> 3;
        const int c0  = (tid & 7) * 4;
        const float* hp = h + (long)ssrc[row] * IN;
        float* dst = &hsm[row * 132];
#pragma unroll
        for (int j = 0; j < 4; ++j) {
            float4 v = *reinterpret_cast<const float4*>(hp + c0 + 32 * j);
            *reinterpret_cast<float4*>(dst + c0 + 32 * j) = v;
        }
    }
    __syncthreads();

    const int slot = tid >> 7;           // 0,1
    const int o    = tid & 127;
    const int b    = o >> 4;
    const int ol   = o & 15;

#define MSG_BODY(K, W0, W1, W2, W3)                                          \
    {                                                                        \
        const float* hrow = &hsm[(K) * 132 + b * 16];                        \
        float4 h0 = *reinterpret_cast<const float4*>(hrow);                  \
        float4 h1 = *reinterpret_cast<const float4*>(hrow + 4);              \
        float4 h2 = *reinterpret_cast<const float4*>(hrow + 8);              \
        float4 h3 = *reinterpret_cast<const float4*>(hrow + 12);             \
        float m0 = 0.f, m1 = 0.f;                                            \
        m0 = fmaf(h0.x, W0.x, m0); m0 = fmaf(h0.y, W0.y, m0);                \
        m0 = fmaf(h0.z, W0.z, m0); m0 = fmaf(h0.w, W0.w, m0);                \
        m1 = fmaf(h1.x, W1.x, m1); m1 = fmaf(h1.y, W1.y, m1);                \
        m1 = fmaf(h1.z, W1.z, m1); m1 = fmaf(h1.w, W1.w, m1);                \
        m0 = fmaf(h2.x, W2.x, m0); m0 = fmaf(h2.y, W2.y, m0);                \
        m0 = fmaf(h2.z, W2.z, m0); m0 = fmaf(h2.w, W2.w, m0);                \
        m1 = fmaf(h3.x, W3.x, m1); m1 = fmaf(h3.y, W3.y, m1);                \
        m1 = fmaf(h3.z, W3.z, m1); m1 = fmaf(h3.w, W3.w, m1);                \
        __builtin_nontemporal_store(f2bf(snorm[K] * (m0 + m1)),              \
                                    &g_msg[(long)spos[K] * OUT + o]);        \
    }

    if (stype[0] == stype[31]) {
        const float4* wp = reinterpret_cast<const float4*>(
            g_W_t + (long)stype[0] * 2048 + b * 256 + ol * 16);
        float4 w0 = wp[0], w1 = wp[1], w2 = wp[2], w3 = wp[3];
#pragma unroll 4
        for (int k = slot; k < 32; k += 2)
            MSG_BODY(k, w0, w1, w2, w3)
    } else {
        int rcur = -1;
        float4 w0, w1, w2, w3;
        for (int k = slot; k < 32; k += 2) {
            int r = stype[k];
            if (r != rcur) {
                const float4* wp = reinterpret_cast<const float4*>(
                    g_W_t + (long)r * 2048 + b * 256 + ol * 16);
                w0 = wp[0]; w1 = wp[1]; w2 = wp[2]; w3 = wp[3];
                rcur = r;
            }
            MSG_BODY(k, w0, w1, w2, w3)
        }
    }
#undef MSG_BODY
}

// Latency-oriented node kernel (round 7): 16 nodes/block, 256 threads =
// 4 waves x 64 feature-pairs, each wave owns 4 independent nodes. No LDS,
// no barriers, no bank conflicts. msg read as uint bf16-pairs (4B/lane
// coalesced); h via wave-broadcast float4; float2 IO elsewhere.
__global__ __launch_bounds__(256) void node_kernel(
        const float* __restrict__ h,
        const float* __restrict__ node_norm,
        const float* __restrict__ h_bias,
        const float* __restrict__ loop_weight,
        const float* __restrict__ time_embed,
        const int* __restrict__ time_idx,
        float* __restrict__ out) {
    const int t    = threadIdx.x;
    const int q    = t & 63;             // feature pair: features 2q, 2q+1
    const int grp  = t >> 6;             // 0..3
    const int base = blockIdx.x * 16 + grp * 4;

    const unsigned* msg32 = reinterpret_cast<const unsigned*>(g_msg);

    float accL[4], accH[4];
#pragma unroll
    for (int nl = 0; nl < 4; ++nl) {
        const int n  = base + nl;
        const int st = g_off_d[n];
        const int cn = g_cnt_d[n];
        const unsigned* mp = msg32 + (size_t)st * 64 + q;
        float aL0 = 0.f, aL1 = 0.f, aH0 = 0.f, aH1 = 0.f;
        int k = 0;
        for (; k + 3 < cn; k += 4) {
            unsigned m0 = __builtin_nontemporal_load(mp + (size_t)(k + 0) * 64);
            unsigned m1 = __builtin_nontemporal_load(mp + (size_t)(k + 1) * 64);
            unsigned m2 = __builtin_nontemporal_load(mp + (size_t)(k + 2) * 64);
            unsigned m3 = __builtin_nontemporal_load(mp + (size_t)(k + 3) * 64);
            aL0 += bflo(m0); aH0 += bfhi(m0);
            aL1 += bflo(m1); aH1 += bfhi(m1);
            aL0 += bflo(m2); aH0 += bfhi(m2);
            aL1 += bflo(m3); aH1 += bfhi(m3);
        }
        for (; k < cn; ++k) {
            unsigned m = __builtin_nontemporal_load(mp + (size_t)k * 64);
            aL0 += bflo(m); aH0 += bfhi(m);
        }
        float nn = node_norm[n];
        accL[nl] = (aL0 + aL1) * nn;
        accH[nl] = (aH0 + aH1) * nn;
    }

    float slL0 = 0.f, slL1 = 0.f, slL2 = 0.f, slL3 = 0.f;
    float slH0 = 0.f, slH1 = 0.f, slH2 = 0.f, slH3 = 0.f;
    const float2* lw2 = reinterpret_cast<const float2*>(loop_weight);
    const float* hp0 = h + (size_t)(base + 0) * IN;
    const float* hp1 = h + (size_t)(base + 1) * IN;
    const float* hp2 = h + (size_t)(base + 2) * IN;
    const float* hp3 = h + (size_t)(base + 3) * IN;
#pragma unroll 4
    for (int i0 = 0; i0 < IN; i0 += 4) {
        float2 w0 = lw2[(size_t)(i0 + 0) * 64 + q];
        float2 w1 = lw2[(size_t)(i0 + 1) * 64 + q];
        float2 w2 = lw2[(size_t)(i0 + 2) * 64 + q];
        float2 w3 = lw2[(size_t)(i0 + 3) * 64 + q];
        float4 v0 = *reinterpret_cast<const float4*>(hp0 + i0);
        float4 v1 = *reinterpret_cast<const float4*>(hp1 + i0);
        float4 v2 = *reinterpret_cast<const float4*>(hp2 + i0);
        float4 v3 = *reinterpret_cast<const float4*>(hp3 + i0);
        slL0 = fmaf(v0.x, w0.x, slL0); slL0 = fmaf(v0.y, w1.x, slL0);
        slL0 = fmaf(v0.z, w2.x, slL0); slL0 = fmaf(v0.w, w3.x, slL0);
        slH0 = fmaf(v0.x, w0.y, slH0); slH0 = fmaf(v0.y, w1.y, slH0);
        slH0 = fmaf(v0.z, w2.y, slH0); slH0 = fmaf(v0.w, w3.y, slH0);
        slL1 = fmaf(v1.x, w0.x, slL1); slL1 = fmaf(v1.y, w1.x, slL1);
        slL1 = fmaf(v1.z, w2.x, slL1); slL1 = fmaf(v1.w, w3.x, slL1);
        slH1 = fmaf(v1.x, w0.y, slH1); slH1 = fmaf(v1.y, w1.y, slH1);
        slH1 = fmaf(v1.z, w2.y, slH1); slH1 = fmaf(v1.w, w3.y, slH1);
        slL2 = fmaf(v2.x, w0.x, slL2); slL2 = fmaf(v2.y, w1.x, slL2);
        slL2 = fmaf(v2.z, w2.x, slL2); slL2 = fmaf(v2.w, w3.x, slL2);
        slH2 = fmaf(v2.x, w0.y, slH2); slH2 = fmaf(v2.y, w1.y, slH2);
        slH2 = fmaf(v2.z, w2.y, slH2); slH2 = fmaf(v2.w, w3.y, slH2);
        slL3 = fmaf(v3.x, w0.x, slL3); slL3 = fmaf(v3.y, w1.x, slL3);
        slL3 = fmaf(v3.z, w2.x, slL3); slL3 = fmaf(v3.w, w3.x, slL3);
        slH3 = fmaf(v3.x, w0.y, slH3); slH3 = fmaf(v3.y, w1.y, slH3);
        slH3 = fmaf(v3.z, w2.y, slH3); slH3 = fmaf(v3.w, w3.y, slH3);
    }
    float slL[4] = {slL0, slL1, slL2, slL3};
    float slH[4] = {slH0, slH1, slH2, slH3};

    const float2 bias = reinterpret_cast<const float2*>(h_bias)[q];
    float2* o2  = reinterpret_cast<float2*>(out);
    float2* o2b = reinterpret_cast<float2*>(out + (size_t)N * OUT);
    const float2* te2 = reinterpret_cast<const float2*>(time_embed);
#pragma unroll
    for (int nl = 0; nl < 4; ++nl) {
        const int n = base + nl;
        float2 v;
        v.x = fmaxf(accL[nl] + bias.x + slL[nl], 0.f);
        v.y = fmaxf(accH[nl] + bias.y + slH[nl], 0.f);
        o2[(size_t)n * 64 + q] = v;
        o2b[(size_t)n * 64 + q] = te2[(size_t)time_idx[n] * 64 + q];
    }

    // ---- next-launch counter zeroing (after all g_cnt_d reads) ----
    __syncthreads();
    if (t < 16) g_cnt_d[blockIdx.x * 16 + t] = 0;
    {
        int j = blockIdx.x * 256 + t;           // blocks 0..114 cover NSEG*16
        if (j < NSEG * 16) g_cnt_r[j] = 0;
    }
    if (blockIdx.x == 0 && t == 0) g_done = 0u;
}

extern "C" void kernel_launch(void* const* d_in, const int* in_sizes, int n_in,
                              void* d_out, int out_size, void* d_ws, size_t ws_size,
                              hipStream_t stream) {
    const float* h           = (const float*)d_in[0];
    const float* edge_norm   = (const float*)d_in[1];
    const float* node_norm   = (const float*)d_in[2];
    const float* weight      = (const float*)d_in[3];
    const float* h_bias      = (const float*)d_in[4];
    const float* loop_weight = (const float*)d_in[5];
    const float* time_embed  = (const float*)d_in[6];
    const int*   edge_src    = (const int*)d_in[7];
    const int*   edge_dst    = (const int*)d_in[8];
    const int*   edge_type   = (const int*)d_in[9];
    const int*   time_idx    = (const int*)d_in[10];
    float* out = (float*)d_out;

    build_kernel<<<400, 256, 0, stream>>>(weight, edge_dst, edge_type);
    scatter_kernel<<<(E + 255) / 256, 256, 0, stream>>>(edge_dst, edge_type);
    msg_kernel<<<E / 32, 256, 0, stream>>>(h, edge_norm, edge_src, edge_type);
    node_kernel<<<N / 16, 256, 0, stream>>>(h, node_norm, h_bias, loop_weight,
                                            time_embed, time_idx, out);
}

// Round 9
// 222.130 us; speedup vs baseline: 1.3429x; 1.2828x over previous
//
#include <hip/hip_runtime.h>

#define N 20000
#define E 200000
#define IN 128
#define OUT 128
#define NB 8
#define SI 16
#define SO 16
#define R 230
#define T 365

#define NSH 8                 // relation cursor shards (contention /8)
#define NSEG (R * NSH)        // 1840 (r,shard) segments

// Scratch in module .bss (zero-initialized at load). d_ws untouched;
// kernel_launch does plain kernel launches only (graph-capture safe).
// Counter invariant: node_kernel's tail re-zeroes all counters for the NEXT
// launch; the first launch rides .bss zero-init. g_cur_d is rebuilt from
// g_off_d by alloc_kernel every launch.
__device__ float  g_W_t[(size_t)R * NB * SO * SI]; // W transposed: [r][b][ol][i]
__device__ ushort g_msg[(size_t)E * OUT];          // messages (bf16), dst-packed
__device__ int    g_cnt_d[N];
__device__ int    g_off_d[N];
__device__ int    g_cur_d[N];                      // bumped by msg_kernel
__device__ int    g_cnt_r[NSEG * 16];              // line-padded (r,shard) counts
__device__ int    g_cur_r[NSEG * 16];
__device__ int    g_eid_r[E];                      // edge ids, (r,shard)-sorted
__device__ int    g_total_d;
__device__ int    g_total_r;

__device__ __forceinline__ ushort f2bf(float f) {  // RNE float->bf16
    unsigned u = __float_as_uint(f);
    return (ushort)((u + 0x7fffu + ((u >> 16) & 1u)) >> 16);
}
__device__ __forceinline__ float bflo(unsigned m) { return __uint_as_float(m << 16); }
__device__ __forceinline__ float bfhi(unsigned m) { return __uint_as_float(m & 0xffff0000u); }

// W transpose + dst histogram (direct atomics) + sharded relation histogram
// (LDS-aggregated). Separate kernel: fusing alloc behind a last-block tail
// lost 55-70 us in rounds 7-8 (single-block serialization).
__global__ __launch_bounds__(256) void hist_kernel(
        const float* __restrict__ weight,
        const int* __restrict__ edge_dst,
        const int* __restrict__ edge_type) {
    __shared__ int lh[NSEG];
    const int tid  = threadIdx.x;
    const int gtid = blockIdx.x * 256 + tid;
    const int GSZ  = gridDim.x * 256;

    for (int t = gtid; t < R * NB * SI * SO; t += GSZ) {
        int r  = t >> 11;
        int b  = (t >> 8) & 7;
        int ol = (t >> 4) & 15;
        int i  = t & 15;
        g_W_t[t] = weight[(long)r * 2048 + b * 256 + i * 16 + ol];
    }
    for (int j = tid; j < NSEG; j += 256) lh[j] = 0;
    __syncthreads();
    for (int e = gtid; e < E; e += GSZ) {
        atomicAdd(&g_cnt_d[edge_dst[e]], 1);
        atomicAdd(&lh[edge_type[e] * NSH + (e & (NSH - 1))], 1);
    }
    __syncthreads();
    for (int j = tid; j < NSEG; j += 256)
        if (lh[j]) atomicAdd(&g_cnt_r[j * 16], lh[j]);
}

// Wave-aggregated bump allocation (one global atomic per wave) — the R6
// proven pattern. idx space: [0,20032) dst slots, [20032, 20032+1856) rel
// segment slots (both wave-aligned).
__global__ __launch_bounds__(256) void alloc_kernel() {
    const int idx  = blockIdx.x * blockDim.x + threadIdx.x;
    const int lane = threadIdx.x & 63;
    const int NPAD = 20032;                       // 313 waves
    if (idx < NPAD) {
        int c = (idx < N) ? g_cnt_d[idx] : 0;
        int x = c;
        for (int d = 1; d < 64; d <<= 1) {
            int y = __shfl_up(x, d);
            if (lane >= d) x += y;
        }
        int base = 0;
        if (lane == 63) base = atomicAdd(&g_total_d, x);
        base = __shfl(base, 63);
        if (idx < N) {
            int off = base + x - c;
            g_off_d[idx] = off;
            g_cur_d[idx] = off;
        }
    } else {
        int j = idx - NPAD;                        // [0, 1856) covers NSEG
        if (j < 1856) {
            int c = (j < NSEG) ? g_cnt_r[j * 16] : 0;
            int x = c;
            for (int d = 1; d < 64; d <<= 1) {
                int y = __shfl_up(x, d);
                if (lane >= d) x += y;
            }
            int base = 0;
            if (lane == 63) base = atomicAdd(&g_total_r, x);
            base = __shfl(base, 63);
            if (j < NSEG) g_cur_r[j * 16] = base + x - c;
        }
    }
}

// Relation-scatter only: the dst-position assignment moved into msg_kernel
// (node needs contiguity per dst, not a specific order) — halves this
// kernel's atomic traffic and deletes g_pos entirely.
__global__ void scatter_kernel(const int* __restrict__ edge_type) {
    int e = blockIdx.x * blockDim.x + threadIdx.x;
    if (e < E) {
        int seg = edge_type[e] * NSH + (e & (NSH - 1));
        int pr = atomicAdd(&g_cur_r[seg * 16], 1);
        g_eid_r[pr] = e;
    }
}

// Block-pipelined message kernel, 32-edge tiles (verified rounds 6-8).
// Meta phase now also claims each edge's dst-packed slot via one atomic
// per edge (32/block, latency hidden before the gather barrier).
__global__ __launch_bounds__(256) void msg_kernel(
        const float* __restrict__ h,
        const float* __restrict__ edge_norm,
        const int* __restrict__ edge_src,
        const int* __restrict__ edge_dst,
        const int* __restrict__ edge_type) {
    __shared__ __attribute__((aligned(16))) float hsm[32 * 132];
    __shared__ int   ssrc[32], stype[32], spos[32];
    __shared__ float snorm[32];

    const int tid = threadIdx.x;
    const int lo  = blockIdx.x * 32;

    if (tid < 32) {
        int e = g_eid_r[lo + tid];
        ssrc[tid]  = edge_src[e];
        stype[tid] = edge_type[e];
        snorm[tid] = edge_norm[e];
        spos[tid]  = atomicAdd(&g_cur_d[edge_dst[e]], 1);
    }
    __syncthreads();

    {   // gather 32 h-rows: 8 threads/row, 4 float4 each
        const int row = tid >> 3;
        const int c0  = (tid & 7) * 4;
        const float* hp = h + (long)ssrc[row] * IN;
        float* dst = &hsm[row * 132];
#pragma unroll
        for (int j = 0; j < 4; ++j) {
            float4 v = *reinterpret_cast<const float4*>(hp + c0 + 32 * j);
            *reinterpret_cast<float4*>(dst + c0 + 32 * j) = v;
        }
    }
    __syncthreads();

    const int slot = tid >> 7;           // 0,1
    const int o    = tid & 127;
    const int b    = o >> 4;
    const int ol   = o & 15;

#define MSG_BODY(K, W0, W1, W2, W3)                                          \
    {                                                                        \
        const float* hrow = &hsm[(K) * 132 + b * 16];                        \
        float4 h0 = *reinterpret_cast<const float4*>(hrow);                  \
        float4 h1 = *reinterpret_cast<const float4*>(hrow + 4);              \
        float4 h2 = *reinterpret_cast<const float4*>(hrow + 8);              \
        float4 h3 = *reinterpret_cast<const float4*>(hrow + 12);             \
        float m0 = 0.f, m1 = 0.f;                                            \
        m0 = fmaf(h0.x, W0.x, m0); m0 = fmaf(h0.y, W0.y, m0);                \
        m0 = fmaf(h0.z, W0.z, m0); m0 = fmaf(h0.w, W0.w, m0);                \
        m1 = fmaf(h1.x, W1.x, m1); m1 = fmaf(h1.y, W1.y, m1);                \
        m1 = fmaf(h1.z, W1.z, m1); m1 = fmaf(h1.w, W1.w, m1);                \
        m0 = fmaf(h2.x, W2.x, m0); m0 = fmaf(h2.y, W2.y, m0);                \
        m0 = fmaf(h2.z, W2.z, m0); m0 = fmaf(h2.w, W2.w, m0);                \
        m1 = fmaf(h3.x, W3.x, m1); m1 = fmaf(h3.y, W3.y, m1);                \
        m1 = fmaf(h3.z, W3.z, m1); m1 = fmaf(h3.w, W3.w, m1);                \
        __builtin_nontemporal_store(f2bf(snorm[K] * (m0 + m1)),              \
                                    &g_msg[(long)spos[K] * OUT + o]);        \
    }

    if (stype[0] == stype[31]) {
        const float4* wp = reinterpret_cast<const float4*>(
            g_W_t + (long)stype[0] * 2048 + b * 256 + ol * 16);
        float4 w0 = wp[0], w1 = wp[1], w2 = wp[2], w3 = wp[3];
#pragma unroll 4
        for (int k = slot; k < 32; k += 2)
            MSG_BODY(k, w0, w1, w2, w3)
    } else {
        int rcur = -1;
        float4 w0, w1, w2, w3;
        for (int k = slot; k < 32; k += 2) {
            int r = stype[k];
            if (r != rcur) {
                const float4* wp = reinterpret_cast<const float4*>(
                    g_W_t + (long)r * 2048 + b * 256 + ol * 16);
                w0 = wp[0]; w1 = wp[1]; w2 = wp[2]; w3 = wp[3];
                rcur = r;
            }
            MSG_BODY(k, w0, w1, w2, w3)
        }
    }
#undef MSG_BODY
}

// Latency-oriented node kernel (verified rounds 7-8): 16 nodes/block,
// 256 threads = 4 waves x 64 feature-pairs, each wave owns 4 independent
// nodes. No LDS, no bank conflicts. msg read as uint bf16-pairs; h via
// wave-broadcast float4; float2 IO elsewhere. Tail re-zeroes counters.
__global__ __launch_bounds__(256) void node_kernel(
        const float* __restrict__ h,
        const float* __restrict__ node_norm,
        const float* __restrict__ h_bias,
        const float* __restrict__ loop_weight,
        const float* __restrict__ time_embed,
        const int* __restrict__ time_idx,
        float* __restrict__ out) {
    const int t    = threadIdx.x;
    const int q    = t & 63;             // feature pair: features 2q, 2q+1
    const int grp  = t >> 6;             // 0..3
    const int base = blockIdx.x * 16 + grp * 4;

    const unsigned* msg32 = reinterpret_cast<const unsigned*>(g_msg);

    float accL[4], accH[4];
#pragma unroll
    for (int nl = 0; nl < 4; ++nl) {
        const int n  = base + nl;
        const int st = g_off_d[n];
        const int cn = g_cnt_d[n];
        const unsigned* mp = msg32 + (size_t)st * 64 + q;
        float aL0 = 0.f, aL1 = 0.f, aH0 = 0.f, aH1 = 0.f;
        int k = 0;
        for (; k + 3 < cn; k += 4) {
            unsigned m0 = __builtin_nontemporal_load(mp + (size_t)(k + 0) * 64);
            unsigned m1 = __builtin_nontemporal_load(mp + (size_t)(k + 1) * 64);
            unsigned m2 = __builtin_nontemporal_load(mp + (size_t)(k + 2) * 64);
            unsigned m3 = __builtin_nontemporal_load(mp + (size_t)(k + 3) * 64);
            aL0 += bflo(m0); aH0 += bfhi(m0);
            aL1 += bflo(m1); aH1 += bfhi(m1);
            aL0 += bflo(m2); aH0 += bfhi(m2);
            aL1 += bflo(m3); aH1 += bfhi(m3);
        }
        for (; k < cn; ++k) {
            unsigned m = __builtin_nontemporal_load(mp + (size_t)k * 64);
            aL0 += bflo(m); aH0 += bfhi(m);
        }
        float nn = node_norm[n];
        accL[nl] = (aL0 + aL1) * nn;
        accH[nl] = (aH0 + aH1) * nn;
    }

    float slL0 = 0.f, slL1 = 0.f, slL2 = 0.f, slL3 = 0.f;
    float slH0 = 0.f, slH1 = 0.f, slH2 = 0.f, slH3 = 0.f;
    const float2* lw2 = reinterpret_cast<const float2*>(loop_weight);
    const float* hp0 = h + (size_t)(base + 0) * IN;
    const float* hp1 = h + (size_t)(base + 1) * IN;
    const float* hp2 = h + (size_t)(base + 2) * IN;
    const float* hp3 = h + (size_t)(base + 3) * IN;
#pragma unroll 4
    for (int i0 = 0; i0 < IN; i0 += 4) {
        float2 w0 = lw2[(size_t)(i0 + 0) * 64 + q];
        float2 w1 = lw2[(size_t)(i0 + 1) * 64 + q];
        float2 w2 = lw2[(size_t)(i0 + 2) * 64 + q];
        float2 w3 = lw2[(size_t)(i0 + 3) * 64 + q];
        float4 v0 = *reinterpret_cast<const float4*>(hp0 + i0);
        float4 v1 = *reinterpret_cast<const float4*>(hp1 + i0);
        float4 v2 = *reinterpret_cast<const float4*>(hp2 + i0);
        float4 v3 = *reinterpret_cast<const float4*>(hp3 + i0);
        slL0 = fmaf(v0.x, w0.x, slL0); slL0 = fmaf(v0.y, w1.x, slL0);
        slL0 = fmaf(v0.z, w2.x, slL0); slL0 = fmaf(v0.w, w3.x, slL0);
        slH0 = fmaf(v0.x, w0.y, slH0); slH0 = fmaf(v0.y, w1.y, slH0);
        slH0 = fmaf(v0.z, w2.y, slH0); slH0 = fmaf(v0.w, w3.y, slH0);
        slL1 = fmaf(v1.x, w0.x, slL1); slL1 = fmaf(v1.y, w1.x, slL1);
        slL1 = fmaf(v1.z, w2.x, slL1); slL1 = fmaf(v1.w, w3.x, slL1);
        slH1 = fmaf(v1.x, w0.y, slH1); slH1 = fmaf(v1.y, w1.y, slH1);
        slH1 = fmaf(v1.z, w2.y, slH1); slH1 = fmaf(v1.w, w3.y, slH1);
        slL2 = fmaf(v2.x, w0.x, slL2); slL2 = fmaf(v2.y, w1.x, slL2);
        slL2 = fmaf(v2.z, w2.x, slL2); slL2 = fmaf(v2.w, w3.x, slL2);
        slH2 = fmaf(v2.x, w0.y, slH2); slH2 = fmaf(v2.y, w1.y, slH2);
        slH2 = fmaf(v2.z, w2.y, slH2); slH2 = fmaf(v2.w, w3.y, slH2);
        slL3 = fmaf(v3.x, w0.x, slL3); slL3 = fmaf(v3.y, w1.x, slL3);
        slL3 = fmaf(v3.z, w2.x, slL3); slL3 = fmaf(v3.w, w3.x, slL3);
        slH3 = fmaf(v3.x, w0.y, slH3); slH3 = fmaf(v3.y, w1.y, slH3);
        slH3 = fmaf(v3.z, w2.y, slH3); slH3 = fmaf(v3.w, w3.y, slH3);
    }
    float slL[4] = {slL0, slL1, slL2, slL3};
    float slH[4] = {slH0, slH1, slH2, slH3};

    const float2 bias = reinterpret_cast<const float2*>(h_bias)[q];
    float2* o2  = reinterpret_cast<float2*>(out);
    float2* o2b = reinterpret_cast<float2*>(out + (size_t)N * OUT);
    const float2* te2 = reinterpret_cast<const float2*>(time_embed);
#pragma unroll
    for (int nl = 0; nl < 4; ++nl) {
        const int n = base + nl;
        float2 v;
        v.x = fmaxf(accL[nl] + bias.x + slL[nl], 0.f);
        v.y = fmaxf(accH[nl] + bias.y + slH[nl], 0.f);
        o2[(size_t)n * 64 + q] = v;
        o2b[(size_t)n * 64 + q] = te2[(size_t)time_idx[n] * 64 + q];
    }

    // ---- next-launch counter zeroing (after all g_cnt_d reads) ----
    __syncthreads();
    if (t < 16) g_cnt_d[blockIdx.x * 16 + t] = 0;
    {
        int j = blockIdx.x * 256 + t;           // blocks 0..115 cover NSEG*16
        if (j < NSEG * 16) g_cnt_r[j] = 0;
    }
    if (blockIdx.x == 0 && t == 0) { g_total_d = 0; g_total_r = 0; }
}

extern "C" void kernel_launch(void* const* d_in, const int* in_sizes, int n_in,
                              void* d_out, int out_size, void* d_ws, size_t ws_size,
                              hipStream_t stream) {
    const float* h           = (const float*)d_in[0];
    const float* edge_norm   = (const float*)d_in[1];
    const float* node_norm   = (const float*)d_in[2];
    const float* weight      = (const float*)d_in[3];
    const float* h_bias      = (const float*)d_in[4];
    const float* loop_weight = (const float*)d_in[5];
    const float* time_embed  = (const float*)d_in[6];
    const int*   edge_src    = (const int*)d_in[7];
    const int*   edge_dst    = (const int*)d_in[8];
    const int*   edge_type   = (const int*)d_in[9];
    const int*   time_idx    = (const int*)d_in[10];
    float* out = (float*)d_out;

    hist_kernel<<<400, 256, 0, stream>>>(weight, edge_dst, edge_type);
    alloc_kernel<<<86, 256, 0, stream>>>();
    scatter_kernel<<<(E + 255) / 256, 256, 0, stream>>>(edge_type);
    msg_kernel<<<E / 32, 256, 0, stream>>>(h, edge_norm, edge_src,
                                           edge_dst, edge_type);
    node_kernel<<<N / 16, 256, 0, stream>>>(h, node_norm, h_bias, loop_weight,
                                            time_embed, time_idx, out);
}